// Round 1
// baseline (621.687 us; speedup 1.0000x reference)
//
#include <hip/hip_runtime.h>

// ---------------------------------------------------------------------------
// ExpertParallelMoE: top-1 routing, E=8 experts, D=1024, H=4096, C=2048,
// N = 4*2048 = 8192 tokens. bf16 MFMA grouped-GEMM implementation.
// This round: split-K=2 gemm2 (grid was occupancy-limited at 2 blocks/CU),
// gemm1 LDS union (48KB->32KB, 3->5 blocks/CU), vectorized transpose stores.
// ---------------------------------------------------------------------------

#define N_TOK   8192
#define DMODEL  1024
#define HDIM    4096
#define NEXP    8
#define CAP     2048
#define MAXROWS 9216   // sum of per-expert 128-padded counts <= 8192 + 8*127

typedef float  f32x4  __attribute__((ext_vector_type(4)));
typedef __bf16 bf16x8 __attribute__((ext_vector_type(8)));

typedef void __attribute__((address_space(1))) as1_void;
typedef void __attribute__((address_space(3))) as3_void;

__device__ __forceinline__ void async_copy16(void* lds, const void* g) {
    __builtin_amdgcn_global_load_lds((as1_void*)g, (as3_void*)lds, 16, 0, 0);
}

__device__ __forceinline__ unsigned short f2bf(float f) {
    unsigned u = __float_as_uint(f);
    unsigned r = (u + 0x7fffu + ((u >> 16) & 1u)) >> 16;
    return (unsigned short)r;
}

// ---------------------------------------------------------------------------
// 1) Gating: logits = x @ Wg + bg, argmax (first index wins on ties).
//    fp64 accumulation so ordering matches the fp64 numpy reference.
//    One wave per token, 4 tokens per block.
// ---------------------------------------------------------------------------
__global__ __launch_bounds__(256) void gate_kernel(
    const float* __restrict__ x, const float* __restrict__ Wg,
    const float* __restrict__ bg, int* __restrict__ route)
{
    const int wave = threadIdx.x >> 6, lane = threadIdx.x & 63;
    const int tok = blockIdx.x * 4 + wave;
    const float* xr = x + (size_t)tok * DMODEL;
    double acc[8];
#pragma unroll
    for (int e = 0; e < 8; ++e) acc[e] = 0.0;
    for (int i = 0; i < DMODEL / 64; ++i) {
        const int d = i * 64 + lane;
        const double xv = (double)xr[d];
        const float* wr = Wg + (size_t)d * 8;
#pragma unroll
        for (int e = 0; e < 8; ++e) acc[e] += xv * (double)wr[e];
    }
#pragma unroll
    for (int e = 0; e < 8; ++e) {
        double v = acc[e];
#pragma unroll
        for (int off = 32; off > 0; off >>= 1) v += __shfl_down(v, off, 64);
        acc[e] = v;
    }
    if (lane == 0) {
        double bv = acc[0] + (double)bg[0];
        int bi = 0;
#pragma unroll
        for (int e = 1; e < 8; ++e) {
            double v = acc[e] + (double)bg[e];
            if (v > bv) { bv = v; bi = e; }
        }
        route[tok] = bi;
    }
}

// ---------------------------------------------------------------------------
// 2) Scan (single block): token-order positions per expert, capacity clamp,
//    per-expert 128-padded row bases, and row -> token map.
//    meta layout (ints): [0..7]=cnt  [8..15]=padded  [16..23]=rowbase  [24]=total
// ---------------------------------------------------------------------------
__global__ __launch_bounds__(256) void scan_kernel(
    const int* __restrict__ route, int* __restrict__ tokrow,
    int* __restrict__ meta)
{
    __shared__ int hist[256][8];
    __shared__ int cntS[8];
    __shared__ int rowbaseS[8];
    const int tid = threadIdx.x;
    for (int i = tid; i < MAXROWS; i += 256) tokrow[i] = -1;
    const int t0 = tid * 32;
    int r[32];
#pragma unroll
    for (int i = 0; i < 32; ++i) r[i] = route[t0 + i];
    int loc[8];
#pragma unroll
    for (int e = 0; e < 8; ++e) loc[e] = 0;
#pragma unroll
    for (int i = 0; i < 32; ++i) {
#pragma unroll
        for (int e = 0; e < 8; ++e) loc[e] += (r[i] == e) ? 1 : 0;
    }
#pragma unroll
    for (int e = 0; e < 8; ++e) hist[tid][e] = loc[e];
    __syncthreads();
    if (tid < 8) {
        int run = 0;
        for (int t = 0; t < 256; ++t) { int v = hist[t][tid]; hist[t][tid] = run; run += v; }
        meta[tid] = run;
        cntS[tid] = run;
    }
    __syncthreads();
    if (tid == 0) {
        int rb = 0;
#pragma unroll
        for (int e = 0; e < 8; ++e) {
            int c = cntS[e]; if (c > CAP) c = CAP;
            int p = (c + 127) & ~127;
            meta[8 + e] = p;
            meta[16 + e] = rb;
            rowbaseS[e] = rb;
            rb += p;
        }
        meta[24] = rb;
    }
    __syncthreads();
    int base[8];
#pragma unroll
    for (int e = 0; e < 8; ++e) base[e] = hist[tid][e];
#pragma unroll
    for (int i = 0; i < 32; ++i) {
        const int e = r[i];
        const int p = base[e]++;
        if (p < CAP) tokrow[rowbaseS[e] + p] = t0 + i;
    }
}

// ---------------------------------------------------------------------------
// 3) Dispatch: xg[row][:] = bf16(x[token][:]) (zeros for padding rows).
//    One block per row; 256 threads x 4 floats.
// ---------------------------------------------------------------------------
__global__ __launch_bounds__(256) void dispatch_kernel(
    const float* __restrict__ x, const int* __restrict__ tokrow,
    unsigned short* __restrict__ xg)
{
    const int row = blockIdx.x;
    const int tok = tokrow[row];
    const int d = threadIdx.x * 4;
    float4 v = make_float4(0.f, 0.f, 0.f, 0.f);
    if (tok >= 0) v = *(const float4*)(x + (size_t)tok * DMODEL + d);
    ushort4 o;
    o.x = f2bf(v.x); o.y = f2bf(v.y); o.z = f2bf(v.z); o.w = f2bf(v.w);
    *(ushort4*)(xg + (size_t)row * DMODEL + d) = o;
}

// ---------------------------------------------------------------------------
// 4) Weight transpose+cast: in (E,R,C) f32 row-major -> out (E,C,R) bf16.
//    Tile 64(R) x 32(C), block (32,8). ushort2 stores -> full 128B write
//    transactions (previous version stored scalar ushort = half-width).
// ---------------------------------------------------------------------------
__global__ void transpose_cast_kernel(const float* __restrict__ in,
                                      unsigned short* __restrict__ out,
                                      int R, int C)
{
    __shared__ float t[64][33];
    const size_t base = (size_t)blockIdx.z * R * C;
    const int c0 = blockIdx.x * 32, r0 = blockIdx.y * 64;
    const int x = threadIdx.x, y0 = threadIdx.y;   // blockDim (32,8)
#pragma unroll
    for (int i = 0; i < 8; ++i) {
        const int r = y0 + i * 8;
        t[r][x] = in[base + (size_t)(r0 + r) * C + c0 + x];
    }
    __syncthreads();
#pragma unroll
    for (int i = 0; i < 4; ++i) {
        const int c = y0 + i * 8;
        ushort2 o;
        o.x = f2bf(t[2 * x][c]);      // LDS: stride 66 floats -> 2-way (free)
        o.y = f2bf(t[2 * x + 1][c]);
        *(ushort2*)(&out[base + (size_t)(c0 + c) * R + r0 + 2 * x]) = o;
    }
}

// ---------------------------------------------------------------------------
// Shared MFMA main loop: C_tile(128x128) += A(128xKiter) * B^T(128xKiter)^T.
// A/B row-major bf16 with row stride ld (>= Kiter; split-K passes ld=HDIM,
// Kiter=HDIM/2 with pre-offset pointers). m97 structure: global_load_lds
// width-16 staging, BK=32, 4 waves each computing 64x64 via 4x4 grid of
// 16x16x32 bf16 MFMAs. LDS (16KB) now passed in by the caller so gemm1 can
// union it with its epilogue buffer.
// ---------------------------------------------------------------------------
__device__ __forceinline__ void mfma_mainloop(
    const unsigned short* __restrict__ A,
    const unsigned short* __restrict__ B,
    int ld, int Kiter, int tid, char* smem, f32x4 acc[4][4])
{
    const int wave = tid >> 6, lane = tid & 63;
    const int mrow = lane >> 2;            // 0..15
    const int kofs = (lane & 3) * 8;       // k element offset within BK=32
    const int quad = lane >> 4, l16 = lane & 15;
    const int wm = (wave & 1) * 64, wn = (wave >> 1) * 64;

    for (int k0 = 0; k0 < Kiter; k0 += 32) {
        __syncthreads();
#pragma unroll
        for (int i = 0; i < 2; ++i) {
            const int m = wave * 32 + i * 16 + mrow;
            async_copy16(smem + wave * 2048 + i * 1024 + lane * 16,
                         A + (size_t)m * ld + k0 + kofs);
        }
#pragma unroll
        for (int i = 0; i < 2; ++i) {
            const int n = wave * 32 + i * 16 + mrow;
            async_copy16(smem + 8192 + wave * 2048 + i * 1024 + lane * 16,
                         B + (size_t)n * ld + k0 + kofs);
        }
        __syncthreads();
        bf16x8 a[4], b[4];
#pragma unroll
        for (int mi = 0; mi < 4; ++mi)
            a[mi] = *(const bf16x8*)(smem + ((wm + mi * 16 + l16) * 32 + quad * 8) * 2);
#pragma unroll
        for (int ni = 0; ni < 4; ++ni)
            b[ni] = *(const bf16x8*)(smem + 8192 + ((wn + ni * 16 + l16) * 32 + quad * 8) * 2);
#pragma unroll
        for (int mi = 0; mi < 4; ++mi)
#pragma unroll
            for (int ni = 0; ni < 4; ++ni)
                acc[mi][ni] = __builtin_amdgcn_mfma_f32_16x16x32_bf16(
                    a[mi], b[ni], acc[mi][ni], 0, 0, 0);
    }
}

// ---------------------------------------------------------------------------
// 5) GEMM1: h = relu(xg @ W1[e] + b1[e]) -> bf16 hbuf[row][HDIM].
//    Epilogue transposes through LDS for coalesced 16B global stores.
//    LDS union: 32KB total (mainloop uses first 16KB) -> 5 blocks/CU.
// ---------------------------------------------------------------------------
__global__ __launch_bounds__(256) void gemm1_kernel(
    const unsigned short* __restrict__ xg,
    const unsigned short* __restrict__ wb,    // (E, HDIM, DMODEL) bf16
    const float* __restrict__ b1,             // (E, HDIM)
    unsigned short* __restrict__ hbuf,        // (rows, HDIM) bf16
    const int* __restrict__ meta)
{
    const int e = blockIdx.z, mtile = blockIdx.y, ntile = blockIdx.x;
    if (mtile * 128 >= meta[8 + e]) return;
    const int row0 = meta[16 + e] + mtile * 128;
    const int tid = threadIdx.x;

    __shared__ __align__(16) char lds[32768];

    f32x4 acc[4][4];
#pragma unroll
    for (int mi = 0; mi < 4; ++mi)
#pragma unroll
        for (int ni = 0; ni < 4; ++ni)
#pragma unroll
            for (int r = 0; r < 4; ++r) acc[mi][ni][r] = 0.0f;

    mfma_mainloop(xg + (size_t)row0 * DMODEL,
                  wb + ((size_t)e * HDIM + (size_t)ntile * 128) * DMODEL,
                  DMODEL, DMODEL, tid, lds, acc);

    __syncthreads();   // lds is reused as hl below: wait for all waves' reads
    unsigned short* hl = (unsigned short*)lds;   // 128*128 bf16 = 32KB
    const int wave = tid >> 6, lane = tid & 63;
    const int quad = lane >> 4, l16 = lane & 15;
    const int wm = (wave & 1) * 64, wn = (wave >> 1) * 64;
    const float* bias = b1 + (size_t)e * HDIM + (size_t)ntile * 128;
#pragma unroll
    for (int mi = 0; mi < 4; ++mi)
#pragma unroll
        for (int ni = 0; ni < 4; ++ni) {
            const int cc = wn + ni * 16 + l16;
            const float bv = bias[cc];
#pragma unroll
            for (int r = 0; r < 4; ++r) {
                const int rr = wm + mi * 16 + quad * 4 + r;
                hl[rr * 128 + cc] = f2bf(fmaxf(acc[mi][ni][r] + bv, 0.0f));
            }
        }
    __syncthreads();
#pragma unroll
    for (int i = 0; i < 8; ++i) {
        const int c = tid + i * 256;       // 16B chunk index
        const int m = c >> 4;
        const int nb = (c & 15) * 8;
        *(int4*)(hbuf + (size_t)(row0 + m) * HDIM + (size_t)ntile * 128 + nb) =
            *(const int4*)(hl + m * 128 + nb);
    }
}

// ---------------------------------------------------------------------------
// 6) GEMM2: out[token] = h @ W2[e] + b2[e], scattered via tokrow.
//    Split-K (sh=1): blockIdx.z = e*2+s; split 0 writes out+bias directly,
//    split 1 writes f32 partials to pbuf; reduce_kernel adds them.
//    sh=0 reproduces the old single-pass behavior (workspace fallback).
// ---------------------------------------------------------------------------
__global__ __launch_bounds__(256) void gemm2_kernel(
    const unsigned short* __restrict__ hbuf,
    const unsigned short* __restrict__ wb,    // (E, DMODEL, HDIM) bf16
    const float* __restrict__ b2,             // (E, DMODEL)
    const int* __restrict__ tokrow,
    float* __restrict__ out,
    const int* __restrict__ meta,
    float* __restrict__ pbuf,
    int sh)
{
    const int e = blockIdx.z >> sh;
    const int s = blockIdx.z & ((1 << sh) - 1);
    const int mtile = blockIdx.y, ntile = blockIdx.x;
    if (mtile * 128 >= meta[8 + e]) return;
    const int row0 = meta[16 + e] + mtile * 128;
    const int tid = threadIdx.x;
    const int Ks = HDIM >> sh;

    __shared__ __align__(16) char lds[16384];

    f32x4 acc[4][4];
#pragma unroll
    for (int mi = 0; mi < 4; ++mi)
#pragma unroll
        for (int ni = 0; ni < 4; ++ni)
#pragma unroll
            for (int r = 0; r < 4; ++r) acc[mi][ni][r] = 0.0f;

    mfma_mainloop(hbuf + (size_t)row0 * HDIM + (size_t)s * Ks,
                  wb + ((size_t)e * DMODEL + (size_t)ntile * 128) * HDIM + (size_t)s * Ks,
                  HDIM, Ks, tid, lds, acc);

    const int wave = tid >> 6, lane = tid & 63;
    const int quad = lane >> 4, l16 = lane & 15;
    const int wm = (wave & 1) * 64, wn = (wave >> 1) * 64;
#pragma unroll
    for (int mi = 0; mi < 4; ++mi) {
#pragma unroll
        for (int r = 0; r < 4; ++r) {
            const int rowl = wm + mi * 16 + quad * 4 + r;
            const int tok = tokrow[row0 + rowl];
            if (tok >= 0) {
                if (s == 0) {
#pragma unroll
                    for (int ni = 0; ni < 4; ++ni) {
                        const int col = ntile * 128 + wn + ni * 16 + l16;
                        out[(size_t)tok * DMODEL + col] =
                            acc[mi][ni][r] + b2[(size_t)e * DMODEL + col];
                    }
                } else {
#pragma unroll
                    for (int ni = 0; ni < 4; ++ni) {
                        const int col = ntile * 128 + wn + ni * 16 + l16;
                        pbuf[(size_t)(row0 + rowl) * DMODEL + col] = acc[mi][ni][r];
                    }
                }
            }
        }
    }
}

// ---------------------------------------------------------------------------
// 7) Split-K reduction: out[tok] += pbuf[row]. One block per row.
// ---------------------------------------------------------------------------
__global__ __launch_bounds__(256) void reduce_kernel(
    const float* __restrict__ pbuf, const int* __restrict__ tokrow,
    float* __restrict__ out)
{
    const int row = blockIdx.x;
    const int tok = tokrow[row];
    if (tok < 0) return;
    const int d = threadIdx.x * 4;
    f32x4 p = *(const f32x4*)(pbuf + (size_t)row * DMODEL + d);
    f32x4 o = *(f32x4*)(out + (size_t)tok * DMODEL + d);
    o += p;
    *(f32x4*)(out + (size_t)tok * DMODEL + d) = o;
}

// ---------------------------------------------------------------------------
// Launch. Workspace layout (bytes):
//   [0,32K)        route (8192 int)
//   [32K,69632)    tokrow (9216 int)
//   [69632,69732)  meta (25 int)
//   [128K, ~19MB)  xg    (9216 x 1024 bf16)
//   [20MB, ~92MB)  hbuf  (9216 x 4096 bf16)
//   [96MB, 160MB)  wb    (64MB, reused: W1^T bf16 for gemm1, then W2^T)
//   [160MB, ~196MB) pbuf (9216 x 1024 f32)  -- only if ws_size permits
// ---------------------------------------------------------------------------
extern "C" void kernel_launch(void* const* d_in, const int* in_sizes, int n_in,
                              void* d_out, int out_size, void* d_ws, size_t ws_size,
                              hipStream_t stream) {
    (void)in_sizes; (void)n_in; (void)out_size;
    const float* x  = (const float*)d_in[0];
    const float* Wg = (const float*)d_in[1];
    const float* bg = (const float*)d_in[2];
    const float* W1 = (const float*)d_in[3];
    const float* b1 = (const float*)d_in[4];
    const float* W2 = (const float*)d_in[5];
    const float* b2 = (const float*)d_in[6];
    float* out = (float*)d_out;
    char* ws = (char*)d_ws;

    int* route  = (int*)ws;
    int* tokrow = (int*)(ws + 32768);
    int* meta   = (int*)(ws + 69632);
    unsigned short* xg   = (unsigned short*)(ws + (size_t)131072);
    unsigned short* hbuf = (unsigned short*)(ws + (size_t)20 * 1024 * 1024);
    unsigned short* wb   = (unsigned short*)(ws + (size_t)96 * 1024 * 1024);
    float* pbuf = (float*)(ws + (size_t)160 * 1024 * 1024);

    const size_t splitk_need = (size_t)160 * 1024 * 1024
                             + (size_t)MAXROWS * DMODEL * sizeof(float);
    const bool use_splitk = (ws_size >= splitk_need);

    hipMemsetAsync(d_out, 0, (size_t)N_TOK * DMODEL * sizeof(float), stream);

    gate_kernel<<<N_TOK / 4, 256, 0, stream>>>(x, Wg, bg, route);
    scan_kernel<<<1, 256, 0, stream>>>(route, tokrow, meta);
    dispatch_kernel<<<MAXROWS, 256, 0, stream>>>(x, tokrow, xg);

    // W1 (E, D=1024, H=4096) -> wb (E, 4096, 1024) bf16
    transpose_cast_kernel<<<dim3(HDIM / 32, DMODEL / 64, NEXP), dim3(32, 8), 0, stream>>>(
        W1, wb, DMODEL, HDIM);
    gemm1_kernel<<<dim3(HDIM / 128, 16, NEXP), 256, 0, stream>>>(
        xg, wb, b1, hbuf, meta);

    // W2 (E, H=4096, D=1024) -> wb (E, 1024, 4096) bf16  (reuses wb; stream-ordered)
    transpose_cast_kernel<<<dim3(DMODEL / 32, HDIM / 64, NEXP), dim3(32, 8), 0, stream>>>(
        W2, wb, HDIM, DMODEL);

    if (use_splitk) {
        gemm2_kernel<<<dim3(DMODEL / 128, 16, NEXP * 2), 256, 0, stream>>>(
            hbuf, wb, b2, tokrow, out, meta, pbuf, 1);
        reduce_kernel<<<MAXROWS, 256, 0, stream>>>(pbuf, tokrow, out);
    } else {
        gemm2_kernel<<<dim3(DMODEL / 128, 16, NEXP), 256, 0, stream>>>(
            hbuf, wb, b2, tokrow, out, meta, (float*)nullptr, 0);
    }
}

// Round 2
// 581.106 us; speedup vs baseline: 1.0698x; 1.0698x over previous
//
#include <hip/hip_runtime.h>

// ---------------------------------------------------------------------------
// ExpertParallelMoE: top-1 routing, E=8 experts, D=1024, H=4096, C=2048,
// N = 4*2048 = 8192 tokens. bf16 MFMA grouped-GEMM implementation.
// R2: split-K reverted (occupancy was register-capped, not grid-capped;
// runtime Kiter broke unroll -> VALUBusy 3x). Added T1 XCD-chunked swizzle
// (expert-per-XCD) to both GEMMs to cut the 2.4x hbuf over-fetch seen in
// FETCH_SIZE (337MB vs ~133MB compulsory). Transpose: ushort4 stores.
// ---------------------------------------------------------------------------

#define N_TOK   8192
#define DMODEL  1024
#define HDIM    4096
#define NEXP    8
#define CAP     2048
#define MAXROWS 9216   // sum of per-expert 128-padded counts <= 8192 + 8*127

typedef float  f32x4  __attribute__((ext_vector_type(4)));
typedef __bf16 bf16x8 __attribute__((ext_vector_type(8)));

typedef void __attribute__((address_space(1))) as1_void;
typedef void __attribute__((address_space(3))) as3_void;

__device__ __forceinline__ void async_copy16(void* lds, const void* g) {
    __builtin_amdgcn_global_load_lds((as1_void*)g, (as3_void*)lds, 16, 0, 0);
}

__device__ __forceinline__ unsigned short f2bf(float f) {
    unsigned u = __float_as_uint(f);
    unsigned r = (u + 0x7fffu + ((u >> 16) & 1u)) >> 16;
    return (unsigned short)r;
}

// ---------------------------------------------------------------------------
// 1) Gating: logits = x @ Wg + bg, argmax (first index wins on ties).
//    fp64 accumulation so ordering matches the fp64 numpy reference.
//    One wave per token, 4 tokens per block.
// ---------------------------------------------------------------------------
__global__ __launch_bounds__(256) void gate_kernel(
    const float* __restrict__ x, const float* __restrict__ Wg,
    const float* __restrict__ bg, int* __restrict__ route)
{
    const int wave = threadIdx.x >> 6, lane = threadIdx.x & 63;
    const int tok = blockIdx.x * 4 + wave;
    const float* xr = x + (size_t)tok * DMODEL;
    double acc[8];
#pragma unroll
    for (int e = 0; e < 8; ++e) acc[e] = 0.0;
    for (int i = 0; i < DMODEL / 64; ++i) {
        const int d = i * 64 + lane;
        const double xv = (double)xr[d];
        const float* wr = Wg + (size_t)d * 8;
#pragma unroll
        for (int e = 0; e < 8; ++e) acc[e] += xv * (double)wr[e];
    }
#pragma unroll
    for (int e = 0; e < 8; ++e) {
        double v = acc[e];
#pragma unroll
        for (int off = 32; off > 0; off >>= 1) v += __shfl_down(v, off, 64);
        acc[e] = v;
    }
    if (lane == 0) {
        double bv = acc[0] + (double)bg[0];
        int bi = 0;
#pragma unroll
        for (int e = 1; e < 8; ++e) {
            double v = acc[e] + (double)bg[e];
            if (v > bv) { bv = v; bi = e; }
        }
        route[tok] = bi;
    }
}

// ---------------------------------------------------------------------------
// 2) Scan (single block): token-order positions per expert, capacity clamp,
//    per-expert 128-padded row bases, and row -> token map.
//    meta layout (ints): [0..7]=cnt  [8..15]=padded  [16..23]=rowbase  [24]=total
// ---------------------------------------------------------------------------
__global__ __launch_bounds__(256) void scan_kernel(
    const int* __restrict__ route, int* __restrict__ tokrow,
    int* __restrict__ meta)
{
    __shared__ int hist[256][8];
    __shared__ int cntS[8];
    __shared__ int rowbaseS[8];
    const int tid = threadIdx.x;
    for (int i = tid; i < MAXROWS; i += 256) tokrow[i] = -1;
    const int t0 = tid * 32;
    int r[32];
#pragma unroll
    for (int i = 0; i < 32; ++i) r[i] = route[t0 + i];
    int loc[8];
#pragma unroll
    for (int e = 0; e < 8; ++e) loc[e] = 0;
#pragma unroll
    for (int i = 0; i < 32; ++i) {
#pragma unroll
        for (int e = 0; e < 8; ++e) loc[e] += (r[i] == e) ? 1 : 0;
    }
#pragma unroll
    for (int e = 0; e < 8; ++e) hist[tid][e] = loc[e];
    __syncthreads();
    if (tid < 8) {
        int run = 0;
        for (int t = 0; t < 256; ++t) { int v = hist[t][tid]; hist[t][tid] = run; run += v; }
        meta[tid] = run;
        cntS[tid] = run;
    }
    __syncthreads();
    if (tid == 0) {
        int rb = 0;
#pragma unroll
        for (int e = 0; e < 8; ++e) {
            int c = cntS[e]; if (c > CAP) c = CAP;
            int p = (c + 127) & ~127;
            meta[8 + e] = p;
            meta[16 + e] = rb;
            rowbaseS[e] = rb;
            rb += p;
        }
        meta[24] = rb;
    }
    __syncthreads();
    int base[8];
#pragma unroll
    for (int e = 0; e < 8; ++e) base[e] = hist[tid][e];
#pragma unroll
    for (int i = 0; i < 32; ++i) {
        const int e = r[i];
        const int p = base[e]++;
        if (p < CAP) tokrow[rowbaseS[e] + p] = t0 + i;
    }
}

// ---------------------------------------------------------------------------
// 3) Dispatch: xg[row][:] = bf16(x[token][:]) (zeros for padding rows).
//    One block per row; 256 threads x 4 floats.
// ---------------------------------------------------------------------------
__global__ __launch_bounds__(256) void dispatch_kernel(
    const float* __restrict__ x, const int* __restrict__ tokrow,
    unsigned short* __restrict__ xg)
{
    const int row = blockIdx.x;
    const int tok = tokrow[row];
    const int d = threadIdx.x * 4;
    float4 v = make_float4(0.f, 0.f, 0.f, 0.f);
    if (tok >= 0) v = *(const float4*)(x + (size_t)tok * DMODEL + d);
    ushort4 o;
    o.x = f2bf(v.x); o.y = f2bf(v.y); o.z = f2bf(v.z); o.w = f2bf(v.w);
    *(ushort4*)(xg + (size_t)row * DMODEL + d) = o;
}

// ---------------------------------------------------------------------------
// 4) Weight transpose+cast: in (E,R,C) f32 row-major -> out (E,C,R) bf16.
//    Tile 128(R) x 32(C), block (32,8). ushort4 stores: each output row gets
//    256B contiguous per 32 lanes (full write transactions). LDS pad 33 keeps
//    the strided store-phase reads at a cheap 4-way conflict.
// ---------------------------------------------------------------------------
__global__ __launch_bounds__(256) void transpose_cast_kernel(
    const float* __restrict__ in, unsigned short* __restrict__ out,
    int R, int C)
{
    __shared__ float t[128][33];
    const size_t base = (size_t)blockIdx.z * R * C;
    const int c0 = blockIdx.x * 32, r0 = blockIdx.y * 128;
    const int x = threadIdx.x, y0 = threadIdx.y;   // blockDim (32,8)
#pragma unroll
    for (int i = 0; i < 16; ++i) {
        const int r = y0 + i * 8;
        t[r][x] = in[base + (size_t)(r0 + r) * C + c0 + x];
    }
    __syncthreads();
#pragma unroll
    for (int j = 0; j < 4; ++j) {
        const int c = y0 + j * 8;
        ushort4 o;
        o.x = f2bf(t[4 * x + 0][c]);
        o.y = f2bf(t[4 * x + 1][c]);
        o.z = f2bf(t[4 * x + 2][c]);
        o.w = f2bf(t[4 * x + 3][c]);
        *(ushort4*)(&out[base + (size_t)(c0 + c) * R + r0 + 4 * x]) = o;
    }
}

// ---------------------------------------------------------------------------
// Shared MFMA main loop: C_tile(128x128) += A(128xK) * B^T(128xK)^T.
// A and B both row-major with row stride == K (bf16, compile-time K).
// m97 structure: global_load_lds width-16 staging, BK=32, 4 waves each
// computing 64x64 via 4x4 grid of 16x16x32 bf16 MFMAs.
// ---------------------------------------------------------------------------
__device__ __forceinline__ void mfma_mainloop(
    const unsigned short* __restrict__ A,
    const unsigned short* __restrict__ B,
    int K, int tid, char* smem, f32x4 acc[4][4])
{
    const int wave = tid >> 6, lane = tid & 63;
    const int mrow = lane >> 2;            // 0..15
    const int kofs = (lane & 3) * 8;       // k element offset within BK=32
    const int quad = lane >> 4, l16 = lane & 15;
    const int wm = (wave & 1) * 64, wn = (wave >> 1) * 64;

    for (int k0 = 0; k0 < K; k0 += 32) {
        __syncthreads();
#pragma unroll
        for (int i = 0; i < 2; ++i) {
            const int m = wave * 32 + i * 16 + mrow;
            async_copy16(smem + wave * 2048 + i * 1024 + lane * 16,
                         A + (size_t)m * K + k0 + kofs);
        }
#pragma unroll
        for (int i = 0; i < 2; ++i) {
            const int n = wave * 32 + i * 16 + mrow;
            async_copy16(smem + 8192 + wave * 2048 + i * 1024 + lane * 16,
                         B + (size_t)n * K + k0 + kofs);
        }
        __syncthreads();
        bf16x8 a[4], b[4];
#pragma unroll
        for (int mi = 0; mi < 4; ++mi)
            a[mi] = *(const bf16x8*)(smem + ((wm + mi * 16 + l16) * 32 + quad * 8) * 2);
#pragma unroll
        for (int ni = 0; ni < 4; ++ni)
            b[ni] = *(const bf16x8*)(smem + 8192 + ((wn + ni * 16 + l16) * 32 + quad * 8) * 2);
#pragma unroll
        for (int mi = 0; mi < 4; ++mi)
#pragma unroll
            for (int ni = 0; ni < 4; ++ni)
                acc[mi][ni] = __builtin_amdgcn_mfma_f32_16x16x32_bf16(
                    a[mi], b[ni], acc[mi][ni], 0, 0, 0);
    }
}

// ---------------------------------------------------------------------------
// 5) GEMM1: h = relu(xg @ W1[e] + b1[e]) -> bf16 hbuf[row][HDIM].
//    T1 swizzle: 4096 blocks, 512/XCD = exactly one expert's (32n x 16m)
//    grid per XCD. mtile-fastest within chunk: the 256KB B-slice stays
//    L2-hot while the expert's 2.2MB xg streams (fits 4MB L2 after pass 1).
//    LDS union: 32KB total (mainloop uses first 16KB).
// ---------------------------------------------------------------------------
__global__ __launch_bounds__(256) void gemm1_kernel(
    const unsigned short* __restrict__ xg,
    const unsigned short* __restrict__ wb,    // (E, HDIM, DMODEL) bf16
    const float* __restrict__ b1,             // (E, HDIM)
    unsigned short* __restrict__ hbuf,        // (rows, HDIM) bf16
    const int* __restrict__ meta)
{
    // grid = (32, 16, 8) -> lin in [0,4096); chunk 512 per XCD
    const int lin = blockIdx.x + 32 * (blockIdx.y + 16 * blockIdx.z);
    const int work = (lin & 7) * 512 + (lin >> 3);
    const int e = work >> 9;
    const int rem = work & 511;
    const int mtile = rem & 15, ntile = rem >> 4;
    if (mtile * 128 >= meta[8 + e]) return;
    const int row0 = meta[16 + e] + mtile * 128;
    const int tid = threadIdx.x;

    __shared__ __align__(16) char lds[32768];

    f32x4 acc[4][4];
#pragma unroll
    for (int mi = 0; mi < 4; ++mi)
#pragma unroll
        for (int ni = 0; ni < 4; ++ni)
#pragma unroll
            for (int r = 0; r < 4; ++r) acc[mi][ni][r] = 0.0f;

    mfma_mainloop(xg + (size_t)row0 * DMODEL,
                  wb + ((size_t)e * HDIM + (size_t)ntile * 128) * DMODEL,
                  DMODEL, tid, lds, acc);

    __syncthreads();   // lds is reused as hl below: wait for all waves' reads
    unsigned short* hl = (unsigned short*)lds;   // 128*128 bf16 = 32KB
    const int wave = tid >> 6, lane = tid & 63;
    const int quad = lane >> 4, l16 = lane & 15;
    const int wm = (wave & 1) * 64, wn = (wave >> 1) * 64;
    const float* bias = b1 + (size_t)e * HDIM + (size_t)ntile * 128;
#pragma unroll
    for (int mi = 0; mi < 4; ++mi)
#pragma unroll
        for (int ni = 0; ni < 4; ++ni) {
            const int cc = wn + ni * 16 + l16;
            const float bv = bias[cc];
#pragma unroll
            for (int r = 0; r < 4; ++r) {
                const int rr = wm + mi * 16 + quad * 4 + r;
                hl[rr * 128 + cc] = f2bf(fmaxf(acc[mi][ni][r] + bv, 0.0f));
            }
        }
    __syncthreads();
#pragma unroll
    for (int i = 0; i < 8; ++i) {
        const int c = tid + i * 256;       // 16B chunk index
        const int m = c >> 4;
        const int nb = (c & 15) * 8;
        *(int4*)(hbuf + (size_t)(row0 + m) * HDIM + (size_t)ntile * 128 + nb) =
            *(const int4*)(hl + m * 128 + nb);
    }
}

// ---------------------------------------------------------------------------
// 6) GEMM2: out[token] = h @ W2[e] + b2[e], scattered via tokrow.
//    T1 swizzle: 1024 blocks, 128/XCD = exactly one expert's (8n x 16m)
//    grid per XCD. mtile-fastest: 1MB wb slice L2-hot, hbuf streams.
// ---------------------------------------------------------------------------
__global__ __launch_bounds__(256) void gemm2_kernel(
    const unsigned short* __restrict__ hbuf,
    const unsigned short* __restrict__ wb,    // (E, DMODEL, HDIM) bf16
    const float* __restrict__ b2,             // (E, DMODEL)
    const int* __restrict__ tokrow,
    float* __restrict__ out,
    const int* __restrict__ meta)
{
    // grid = (8, 16, 8) -> lin in [0,1024); chunk 128 per XCD
    const int lin = blockIdx.x + 8 * (blockIdx.y + 16 * blockIdx.z);
    const int work = (lin & 7) * 128 + (lin >> 3);
    const int e = work >> 7;
    const int rem = work & 127;
    const int mtile = rem & 15, ntile = rem >> 4;
    if (mtile * 128 >= meta[8 + e]) return;
    const int row0 = meta[16 + e] + mtile * 128;
    const int tid = threadIdx.x;

    __shared__ __align__(16) char lds[16384];

    f32x4 acc[4][4];
#pragma unroll
    for (int mi = 0; mi < 4; ++mi)
#pragma unroll
        for (int ni = 0; ni < 4; ++ni)
#pragma unroll
            for (int r = 0; r < 4; ++r) acc[mi][ni][r] = 0.0f;

    mfma_mainloop(hbuf + (size_t)row0 * HDIM,
                  wb + ((size_t)e * DMODEL + (size_t)ntile * 128) * HDIM,
                  HDIM, tid, lds, acc);

    const int wave = tid >> 6, lane = tid & 63;
    const int quad = lane >> 4, l16 = lane & 15;
    const int wm = (wave & 1) * 64, wn = (wave >> 1) * 64;
#pragma unroll
    for (int mi = 0; mi < 4; ++mi) {
#pragma unroll
        for (int r = 0; r < 4; ++r) {
            const int rowl = wm + mi * 16 + quad * 4 + r;
            const int tok = tokrow[row0 + rowl];
            if (tok >= 0) {
#pragma unroll
                for (int ni = 0; ni < 4; ++ni) {
                    const int col = ntile * 128 + wn + ni * 16 + l16;
                    out[(size_t)tok * DMODEL + col] =
                        acc[mi][ni][r] + b2[(size_t)e * DMODEL + col];
                }
            }
        }
    }
}

// ---------------------------------------------------------------------------
// Launch. Workspace layout (bytes):
//   [0,32K)        route (8192 int)
//   [32K,69632)    tokrow (9216 int)
//   [69632,69732)  meta (25 int)
//   [128K, ~19MB)  xg    (9216 x 1024 bf16)
//   [20MB, ~92MB)  hbuf  (9216 x 4096 bf16)
//   [96MB, 160MB)  wb    (64MB, reused: W1^T bf16 for gemm1, then W2^T)
// ---------------------------------------------------------------------------
extern "C" void kernel_launch(void* const* d_in, const int* in_sizes, int n_in,
                              void* d_out, int out_size, void* d_ws, size_t ws_size,
                              hipStream_t stream) {
    (void)in_sizes; (void)n_in; (void)out_size; (void)ws_size;
    const float* x  = (const float*)d_in[0];
    const float* Wg = (const float*)d_in[1];
    const float* bg = (const float*)d_in[2];
    const float* W1 = (const float*)d_in[3];
    const float* b1 = (const float*)d_in[4];
    const float* W2 = (const float*)d_in[5];
    const float* b2 = (const float*)d_in[6];
    float* out = (float*)d_out;
    char* ws = (char*)d_ws;

    int* route  = (int*)ws;
    int* tokrow = (int*)(ws + 32768);
    int* meta   = (int*)(ws + 69632);
    unsigned short* xg   = (unsigned short*)(ws + (size_t)131072);
    unsigned short* hbuf = (unsigned short*)(ws + (size_t)20 * 1024 * 1024);
    unsigned short* wb   = (unsigned short*)(ws + (size_t)96 * 1024 * 1024);

    hipMemsetAsync(d_out, 0, (size_t)N_TOK * DMODEL * sizeof(float), stream);

    gate_kernel<<<N_TOK / 4, 256, 0, stream>>>(x, Wg, bg, route);
    scan_kernel<<<1, 256, 0, stream>>>(route, tokrow, meta);
    dispatch_kernel<<<MAXROWS, 256, 0, stream>>>(x, tokrow, xg);

    // W1 (E, D=1024, H=4096) -> wb (E, 4096, 1024) bf16
    transpose_cast_kernel<<<dim3(HDIM / 32, DMODEL / 128, NEXP), dim3(32, 8), 0, stream>>>(
        W1, wb, DMODEL, HDIM);
    gemm1_kernel<<<dim3(HDIM / 128, 16, NEXP), 256, 0, stream>>>(
        xg, wb, b1, hbuf, meta);

    // W2 (E, H=4096, D=1024) -> wb (E, 1024, 4096) bf16  (reuses wb; stream-ordered)
    transpose_cast_kernel<<<dim3(DMODEL / 32, HDIM / 128, NEXP), dim3(32, 8), 0, stream>>>(
        W2, wb, HDIM, DMODEL);
    gemm2_kernel<<<dim3(DMODEL / 128, 16, NEXP), 256, 0, stream>>>(
        hbuf, wb, b2, tokrow, out, meta);
}